// Round 12
// baseline (274.832 us; speedup 1.0000x reference)
//
#include <hip/hip_runtime.h>
#include <hip/hip_bf16.h>

using bf16 = __hip_bfloat16;

#define F 64
#define HG 128
#define HL 128
#define AVG_LOG_INV 0.45511961331341866f  // 1/log(9)
#define BSH 5            // 32 nodes per bucket
#define BNODES 32
#define BCAP 1024        // per-bucket record capacity (mean 512, +22 sigma)
#define BTILE2 4096      // edges per bucket-branch block (512 thr)
#define NBMAX 1664       // LDS hist array size (>= NB)

typedef short short8 __attribute__((ext_vector_type(8)));
typedef float floatx4 __attribute__((ext_vector_type(4)));

__device__ __forceinline__ float b2f(bf16 v) { return __bfloat162float(v); }
__device__ __forceinline__ bf16 f2b(float v) { return __float2bfloat16(v); }
__device__ __forceinline__ short f2bs(float v) { bf16 h = f2b(v); return *(short*)&h; }

__device__ __forceinline__ unsigned packbf2(float x, float y) {
    bf16 a = f2b(x), b = f2b(y);
    unsigned short ua = *(unsigned short*)&a, ub = *(unsigned short*)&b;
    return ((unsigned)ub << 16) | (unsigned)ua;
}

__device__ __forceinline__ float wave_sum(float v) {
    #pragma unroll
    for (int m = 32; m > 0; m >>= 1) v += __shfl_xor(v, m);
    return v;
}

union SmAB {
    struct { int2 recs[BTILE2]; int hist[NBMAX]; int gst[NBMAX]; int lrk[NBMAX]; } bk;
    unsigned short wt[128 * 72];
};

// fused: blocks [0,NBT) bucket-partition edges; blocks [NBT,..) MFMA-stage AB.
// uc computed in the last block. 512 threads.
__global__ void k_abbucket(const float* __restrict__ x, const float* __restrict__ W_pre,
                           bf16* __restrict__ AB, int N,
                           const int* __restrict__ ei, const float* __restrict__ ea,
                           int* __restrict__ gcur, int2* __restrict__ gout, int E, int NB,
                           const float* __restrict__ W_edge, const float* __restrict__ b_edge,
                           const float* __restrict__ b_pre, float* __restrict__ uc, int NBT) {
    __shared__ SmAB sm;
    int t = threadIdx.x;
    int bid = blockIdx.x;

    if (bid < NBT) {  // ---- bucket branch ----
        for (int b = t; b < NB; b += 512) sm.bk.hist[b] = 0;
        __syncthreads();
        int base = bid * BTILE2;
        int lim = E - base; if (lim > BTILE2) lim = BTILE2;
        int nq = ((E & 3) == 0) ? (lim >> 2) : 0;
        const int4* src4 = (const int4*)(ei + base);
        const int4* dst4 = (const int4*)(ei + E + base);
        const float4* ea4 = (const float4*)(ea + base);
        for (int q = t; q < nq; q += 512) {
            int4 s = src4[q], d = dst4[q];
            float4 v = ea4[q];
            int i = q * 4;
            sm.bk.recs[i]     = make_int2((d.x << 16) | s.x, __float_as_int(v.x));
            sm.bk.recs[i + 1] = make_int2((d.y << 16) | s.y, __float_as_int(v.y));
            sm.bk.recs[i + 2] = make_int2((d.z << 16) | s.z, __float_as_int(v.z));
            sm.bk.recs[i + 3] = make_int2((d.w << 16) | s.w, __float_as_int(v.w));
            atomicAdd(&sm.bk.hist[d.x >> BSH], 1);
            atomicAdd(&sm.bk.hist[d.y >> BSH], 1);
            atomicAdd(&sm.bk.hist[d.z >> BSH], 1);
            atomicAdd(&sm.bk.hist[d.w >> BSH], 1);
        }
        for (int i = (nq << 2) + t; i < lim; i += 512) {
            int e = base + i;
            int src = ei[e], dst = ei[E + e];
            sm.bk.recs[i] = make_int2((dst << 16) | src, __float_as_int(ea[e]));
            atomicAdd(&sm.bk.hist[dst >> BSH], 1);
        }
        __syncthreads();
        for (int b = t; b < NB; b += 512) {
            int h = sm.bk.hist[b];
            sm.bk.lrk[b] = 0;
            sm.bk.gst[b] = (h > 0) ? atomicAdd(&gcur[b], h) : 0;
        }
        __syncthreads();
        for (int i = t; i < lim; i += 512) {
            int2 r = sm.bk.recs[i];
            int b = ((unsigned)r.x) >> (16 + BSH);
            int k = atomicAdd(&sm.bk.lrk[b], 1);
            int pos = sm.bk.gst[b] + k;
            if (pos < BCAP) gout[(size_t)b * BCAP + pos] = r;
        }
        return;
    }

    // ---- AB MFMA branch ----
    if (bid == gridDim.x - 1 && t < 64) {
        int f = t;
        float u = 0.f, c = b_pre[f];
        for (int k = 0; k < 64; k++) {
            float w3 = W_pre[(128 + k) * 64 + f];
            u += W_edge[k] * w3;
            c += b_edge[k] * w3;
        }
        uc[f] = u; uc[64 + f] = c;
    }
    for (int idx = t; idx < 8192; idx += 512) {
        int k = idx >> 7, m = idx & 127;
        sm.wt[m * 72 + k] = (unsigned short)f2bs(W_pre[((m & 64) + k) * 64 + (m & 63)]);
    }
    __syncthreads();

    int lane = t & 63;
    int row = lane & 15, quad = lane >> 4;
    int abid = bid - NBT;
    int w = abid * 8 + (t >> 6);
    int nwaves = (gridDim.x - NBT) * 8;
    int ntiles = (N + 15) >> 4;

    for (int tile = w; tile < ntiles; tile += nwaves) {
        int m0 = tile << 4;
        int node_a = m0 + row; if (node_a >= N) node_a = N - 1;
        short8 a[2];
        #pragma unroll
        for (int h = 0; h < 2; h++) {
            const float* xp = x + (size_t)node_a * 64 + h * 32 + quad * 8;
            floatx4 v0 = *(const floatx4*)xp;
            floatx4 v1 = *(const floatx4*)(xp + 4);
            #pragma unroll
            for (int j = 0; j < 4; j++) { a[h][j] = f2bs(v0[j]); a[h][4 + j] = f2bs(v1[j]); }
        }
        #pragma unroll
        for (int s = 0; s < 8; s++) {
            int fbase = s * 16;
            floatx4 c = {0.f, 0.f, 0.f, 0.f};
            #pragma unroll
            for (int h = 0; h < 2; h++) {
                short8 b = *(const short8*)(sm.wt + (fbase + row) * 72 + h * 32 + quad * 8);
                c = __builtin_amdgcn_mfma_f32_16x16x32_bf16(a[h], b, c, 0, 0, 0);
            }
            #pragma unroll
            for (int r = 0; r < 4; r++) {
                int node = m0 + quad * 4 + r;
                if (node < N) AB[(size_t)node * 128 + fbase + row] = f2b(c[r]);
            }
        }
    }
}

// one block (512 thr, 8 waves) per bucket (32 nodes): LDS counting-sort,
// then per-node reduction. Gathers software-pipelined 4-deep.  (R9-proven)
__global__ void k_edge(const bf16* __restrict__ AB, const int2* __restrict__ gout,
                       const int* __restrict__ gcur, const float* __restrict__ uc,
                       bf16* __restrict__ agg, float* __restrict__ ampv, int N) {
    __shared__ int2 recs[BCAP], sortd[BCAP];
    __shared__ int ncnt[BNODES], nofs[BNODES], nrank[BNODES];
    int t = threadIdx.x;  // 512
    int b = blockIdx.x;
    int nn = N - b * BNODES; if (nn > BNODES) nn = BNODES;
    int ecnt = gcur[b]; if (ecnt > BCAP) ecnt = BCAP;

    for (int i = t; i < ecnt; i += 512) recs[i] = gout[(size_t)b * BCAP + i];
    if (t < BNODES) { ncnt[t] = 0; nrank[t] = 0; }
    __syncthreads();
    for (int i = t; i < ecnt; i += 512)
        atomicAdd(&ncnt[((unsigned)recs[i].x >> 16) & (BNODES - 1)], 1);
    __syncthreads();
    if (t < BNODES) {
        int v = ncnt[t], inc = v;
        #pragma unroll
        for (int m = 1; m < BNODES; m <<= 1) { int u = __shfl_up(inc, m); if (t >= m) inc += u; }
        nofs[t] = inc - v;
    }
    __syncthreads();
    for (int i = t; i < ecnt; i += 512) {
        int2 r = recs[i];
        int nl = ((unsigned)r.x >> 16) & (BNODES - 1);
        int k = atomicAdd(&nrank[nl], 1);
        sortd[nofs[nl] + k] = r;
    }
    __syncthreads();

    int lane = t & 63, w = t >> 6;  // 8 waves
    int half = lane & 31, hi32 = lane >> 5;
    float2 u2 = *(const float2*)(uc + 2 * half);
    float2 c2 = *(const float2*)(uc + 64 + 2 * half);

    for (int nl = w; nl < nn; nl += 8) {
        int n = b * BNODES + nl;
        int lo = nofs[nl], cnt = ncnt[nl], hi = lo + cnt;

        unsigned apack = *(const unsigned*)(AB + (size_t)n * 128 + 2 * half);
        float acx = __uint_as_float(apack << 16) + c2.x;
        float acy = __uint_as_float(apack & 0xffff0000u) + c2.y;

        float sx = 0.f, sy = 0.f, qx = 0.f, qy = 0.f;
        float mnx = 3.4e38f, mny = 3.4e38f, mxx = -3.4e38f, mxy = -3.4e38f;

        auto acc2 = [&](unsigned bp, float eav) {
            float bx = __uint_as_float(bp << 16);
            float by = __uint_as_float(bp & 0xffff0000u);
            float m0 = fmaf(eav, u2.x, acx) + bx;
            float m1 = fmaf(eav, u2.y, acy) + by;
            sx += m0; qx = fmaf(m0, m0, qx);
            sy += m1; qy = fmaf(m1, m1, qy);
            mnx = fminf(mnx, m0); mxx = fmaxf(mxx, m0);
            mny = fminf(mny, m1); mxy = fmaxf(mxy, m1);
        };
        auto gaddr = [&](int sn) {
            return (const unsigned*)(AB + (size_t)sn * 128 + 64 + 2 * half);
        };

        for (int base = lo; base < hi; base += 64) {
            int nb = hi - base; if (nb > 64) nb = 64;
            int2 rec = (lane < nb) ? sortd[base + lane] : make_int2(0, 0);
            int vsn = rec.x & 0xFFFF;
            float vea = __int_as_float(rec.y);
            int i = 0;
            for (; i + 8 <= nb; i += 8) {  // 4 pairs in flight
                int sn0 = __shfl(vsn, i + hi32);
                int sn1 = __shfl(vsn, i + 2 + hi32);
                int sn2 = __shfl(vsn, i + 4 + hi32);
                int sn3 = __shfl(vsn, i + 6 + hi32);
                float e0 = __shfl(vea, i + hi32);
                float e1 = __shfl(vea, i + 2 + hi32);
                float e2 = __shfl(vea, i + 4 + hi32);
                float e3 = __shfl(vea, i + 6 + hi32);
                unsigned b0 = *gaddr(sn0);
                unsigned b1 = *gaddr(sn1);
                unsigned b2 = *gaddr(sn2);
                unsigned b3 = *gaddr(sn3);
                acc2(b0, e0); acc2(b1, e1); acc2(b2, e2); acc2(b3, e3);
            }
            for (; i + 2 <= nb; i += 2) {
                int   sn = __shfl(vsn, i + hi32);
                float ev = __shfl(vea, i + hi32);
                acc2(*gaddr(sn), ev);
            }
            if (i < nb) {
                int   sn = __shfl(vsn, i);
                float ev = __shfl(vea, i);
                unsigned bp = *gaddr(sn);
                if (hi32 == 0) acc2(bp, ev);
            }
        }
        sx += __shfl_xor(sx, 32); sy += __shfl_xor(sy, 32);
        qx += __shfl_xor(qx, 32); qy += __shfl_xor(qy, 32);
        mnx = fminf(mnx, __shfl_xor(mnx, 32)); mny = fminf(mny, __shfl_xor(mny, 32));
        mxx = fmaxf(mxx, __shfl_xor(mxx, 32)); mxy = fmaxf(mxy, __shfl_xor(mxy, 32));

        float c1 = (cnt > 0) ? (float)cnt : 1.f;
        float inv = 1.f / c1;
        float mex = sx * inv, mey = sy * inv;
        float vx = qx * inv - mex * mex; if (vx < 0.f) vx = 0.f;
        float vy = qy * inv - mey * mey; if (vy < 0.f) vy = 0.f;
        float sdx = sqrtf(vx + 1e-5f), sdy = sqrtf(vy + 1e-5f);
        if (cnt == 0) { mnx = mny = mxx = mxy = 0.f; }

        size_t ob = (size_t)n * 256 + 2 * half;
        if (hi32 == 0) {
            *(unsigned*)(agg + ob)       = packbf2(mex, mey);
            *(unsigned*)(agg + ob + 64)  = packbf2(mnx, mny);
        } else {
            *(unsigned*)(agg + ob + 128) = packbf2(mxx, mxy);
            *(unsigned*)(agg + ob + 192) = packbf2(sdx, sdy);
        }
        if (lane == 0) ampv[n] = logf(c1 + 1.f) * AVG_LOG_INV;
    }
}

// chunked per-graph SUM of 832-dim feature vector; native fp32 atomic flushes
__global__ void k_greduce2(const float* __restrict__ x, const bf16* __restrict__ agg,
                           const float* __restrict__ ampv, const int* __restrict__ batch,
                           float* __restrict__ gfeat, int* __restrict__ gcnt,
                           int N, int chunk) {
    int t = threadIdx.x;  // 256
    int lo = blockIdx.x * chunk;
    int hi = lo + chunk; if (hi > N) hi = N;
    if (lo >= hi) return;
    int curg = batch[lo];
    float s1 = 0.f, s2 = 0.f, s3 = 0.f, sx = 0.f;
    int cnt = 0;
    for (int n = lo; n < hi; n++) {
        int g = batch[n];
        if (g != curg) {
            float* gf = gfeat + (size_t)curg * 832;
            unsafeAtomicAdd(&gf[64 + t], s1);
            unsafeAtomicAdd(&gf[320 + t], s2);
            unsafeAtomicAdd(&gf[576 + t], s3);
            if (t < 64) unsafeAtomicAdd(&gf[t], sx);
            if (t == 0) atomicAdd(&gcnt[curg], cnt);
            s1 = s2 = s3 = sx = 0.f; cnt = 0; curg = g;
        }
        float amp = ampv[n];
        float av = b2f(agg[(size_t)n * 256 + t]);
        s1 += av; s2 += av * amp; s3 += av / amp;
        if (t < 64) sx += x[(size_t)n * 64 + t];
        cnt++;
    }
    float* gf = gfeat + (size_t)curg * 832;
    unsafeAtomicAdd(&gf[64 + t], s1);
    unsafeAtomicAdd(&gf[320 + t], s2);
    unsafeAtomicAdd(&gf[576 + t], s3);
    if (t < 64) unsafeAtomicAdd(&gf[t], sx);
    if (t == 0) atomicAdd(&gcnt[curg], cnt);
}

__device__ __forceinline__ void gridbar(int* bar, int target) {
    __syncthreads();
    if (threadIdx.x == 0) {
        __threadfence();
        atomicAdd(bar, 1);
        while (__hip_atomic_load(bar, __ATOMIC_ACQUIRE, __HIP_MEMORY_SCOPE_AGENT) < target) {}
    }
    __syncthreads();
}

__device__ void mlp_stage(const float* __restrict__ in, const float* __restrict__ W,
                          const float* __restrict__ bias,
                          const float* __restrict__ gamma, const float* __restrict__ beta,
                          const float* __restrict__ res,
                          const float* __restrict__ g_in, const float* __restrict__ be_in,
                          float* __restrict__ outp, float* A, float* part, int j) {
    int t = threadIdx.x;  // 256
    for (int i = t; i < 8192; i += 256) A[(i >> 7) * 129 + (i & 127)] = in[i];
    __syncthreads();
    if (g_in) {
        if (t < 128) {
            int c = t;
            float mu = 0.f;
            for (int r = 0; r < 64; r++) mu += A[r * 129 + c];
            mu *= (1.f / 64.f);
            float var = 0.f;
            for (int r = 0; r < 64; r++) { float d = A[r * 129 + c] - mu; var += d * d; }
            var *= (1.f / 64.f);
            float sc = rsqrtf(var + 1e-5f) * g_in[c], sh = be_in[c];
            for (int r = 0; r < 64; r++) {
                float v = (A[r * 129 + c] - mu) * sc + sh;
                A[r * 129 + c] = v > 0.f ? v : 0.f;
            }
        }
        __syncthreads();
    }
    int r = t & 63, q = t >> 6;
    float acc = 0.f;
    int k0 = q * 32;
    #pragma unroll
    for (int k = 0; k < 32; k++) acc += A[r * 129 + k0 + k] * W[(k0 + k) * 128 + j];
    part[q * 64 + r] = acc;
    __syncthreads();
    if (t < 64) {
        float v = part[t] + part[64 + t] + part[128 + t] + part[192 + t] + bias[j];
        float mu = wave_sum(v) * (1.f / 64.f);
        float d = v - mu;
        float var = wave_sum(d * d) * (1.f / 64.f);
        float o = d * rsqrtf(var + 1e-5f) * gamma[j] + beta[j];
        if (res) o += res[t * 128 + j];
        outp[t * 128 + j] = o > 0.f ? o : 0.f;
    }
    __syncthreads();
}

// fused tail: post1 + bn1+W2+bn2 + res-block + out, one kernel, 128 co-resident
// blocks (<=1/CU on 256 CUs) with a device-scope counter barrier between stages.
__global__ void __launch_bounds__(256) k_tail(
        const float* __restrict__ gfeat, const int* __restrict__ gcnt,
        const float* __restrict__ W_post, const float* __restrict__ b_post,
        const float* __restrict__ W_lin, const float* __restrict__ b_lin,
        float* __restrict__ Zin,
        const float* g1, const float* be1,
        const float* __restrict__ W2, const float* b2, const float* g2, const float* be2,
        const float* __restrict__ Wr1, const float* br1, const float* gr1, const float* ber1,
        const float* __restrict__ Wr2, const float* br2, const float* gr2, const float* ber2,
        const float* __restrict__ W_out, const float* b_out,
        float* __restrict__ z2b, float* __restrict__ z3b, float* __restrict__ z4b,
        float* __restrict__ out, int* bar, int G) {
    __shared__ float A[64 * 129];
    __shared__ float part[256];
    __shared__ float feat[832];
    __shared__ float z1[128];
    int t = threadIdx.x, bid = blockIdx.x;

    if (bid < G) {  // stage A: post1 for graph bid
        int cg = gcnt[bid];
        float r = 1.f / ((cg > 0) ? (float)cg : 1.f);
        for (int i = t; i < 832; i += 256) feat[i] = gfeat[(size_t)bid * 832 + i] * r;
        __syncthreads();
        if (t < 128) {
            float acc = b_post[t];
            for (int k = 0; k < 832; k++) acc += feat[k] * W_post[k * 128 + t];
            z1[t] = acc;
        }
        __syncthreads();
        if (t < 128) {
            float a2 = b_lin[t];
            for (int k = 0; k < 128; k++) a2 += z1[k] * W_lin[k * 128 + t];
            if (cg == 0) a2 = 0.f;
            Zin[bid * 128 + t] = a2;
        }
    }
    gridbar(bar, 128);
    mlp_stage(Zin, W2, b2, g2, be2, nullptr, g1, be1, z2b, A, part, bid);
    gridbar(bar, 256);
    mlp_stage(z2b, Wr1, br1, gr1, ber1, nullptr, nullptr, nullptr, z3b, A, part, bid);
    gridbar(bar, 384);
    mlp_stage(z3b, Wr2, br2, gr2, ber2, z2b, nullptr, nullptr, z4b, A, part, bid);
    gridbar(bar, 512);
    if (bid == 0 && t < 64) {
        float acc = b_out[0];
        for (int j = 0; j < 128; j++) acc += z4b[t * 128 + j] * W_out[j];
        out[t] = acc;
    }
}

extern "C" void kernel_launch(void* const* d_in, const int* in_sizes, int n_in,
                              void* d_out, int out_size, void* d_ws, size_t ws_size,
                              hipStream_t stream) {
    const float* x      = (const float*)d_in[0];
    const int*   ei     = (const int*)d_in[1];
    const float* ea     = (const float*)d_in[2];
    const int*   batch  = (const int*)d_in[3];
    const float* W_edge = (const float*)d_in[4];
    const float* b_edge = (const float*)d_in[5];
    const float* W_pre  = (const float*)d_in[6];
    const float* b_pre  = (const float*)d_in[7];
    const float* W_post = (const float*)d_in[8];
    const float* b_post = (const float*)d_in[9];
    const float* W_lin  = (const float*)d_in[10];
    const float* b_lin  = (const float*)d_in[11];
    const float* g1     = (const float*)d_in[12];
    const float* be1    = (const float*)d_in[13];
    const float* W2     = (const float*)d_in[14];
    const float* b2     = (const float*)d_in[15];
    const float* g2     = (const float*)d_in[16];
    const float* be2    = (const float*)d_in[17];
    const float* Wr1    = (const float*)d_in[18];
    const float* br1    = (const float*)d_in[19];
    const float* gr1    = (const float*)d_in[20];
    const float* ber1   = (const float*)d_in[21];
    const float* Wr2    = (const float*)d_in[22];
    const float* br2    = (const float*)d_in[23];
    const float* gr2    = (const float*)d_in[24];
    const float* ber2   = (const float*)d_in[25];
    const float* W_out  = (const float*)d_in[26];
    const float* b_out  = (const float*)d_in[27];
    float* out = (float*)d_out;

    const int N = in_sizes[0] / F;      // 50000  (must be <= 65536 for record packing)
    const int E = in_sizes[1] / 2;      // 800000
    const int G = out_size;             // 64
    const int NB = (N + BNODES - 1) >> BSH;  // 1563 buckets
    const int GF = G * 832;

    char* p = (char*)d_ws;
    auto alloc = [&](size_t nbytes) { void* r = p; p += (nbytes + 255) & ~(size_t)255; return r; };
    bf16*  AB     = (bf16*)alloc((size_t)N * 128 * sizeof(bf16));
    bf16*  agg    = (bf16*)alloc((size_t)N * 256 * sizeof(bf16));
    float* ampv   = (float*)alloc((size_t)N * sizeof(float));
    int2*  gout   = (int2*)alloc((size_t)NB * BCAP * sizeof(int2));
    float* uc     = (float*)alloc(128 * sizeof(float));
    float* Zin    = (float*)alloc(64 * 128 * sizeof(float));
    float* z2b    = (float*)alloc(64 * 128 * sizeof(float));
    float* z3b    = (float*)alloc(64 * 128 * sizeof(float));
    float* z4b    = (float*)alloc(64 * 128 * sizeof(float));
    // contiguous zero region: bar | gcur | gcnt | gfeat  (one memset)
    size_t zbytes = (size_t)(1 + NB + G) * sizeof(int) + (size_t)GF * sizeof(float);
    int*   bar    = (int*)alloc(zbytes);
    int*   gcur   = bar + 1;
    int*   gcnt   = gcur + NB;
    float* gfeat  = (float*)(gcnt + G);

    const int GRB = 1024;
    const int GRCH = (N + GRB - 1) / GRB;
    const int NBT = (E + BTILE2 - 1) / BTILE2;          // 196 bucket blocks
    const int ABB = (((N + 15) / 16) + 7) / 8;          // 391 AB blocks (8 waves each)

    hipMemsetAsync(bar, 0, zbytes, stream);
    k_abbucket<<<NBT + ABB, 512, 0, stream>>>(x, W_pre, AB, N, ei, ea, gcur, gout, E, NB,
                                              W_edge, b_edge, b_pre, uc, NBT);
    k_edge<<<NB, 512, 0, stream>>>(AB, gout, gcur, uc, agg, ampv, N);
    k_greduce2<<<GRB, 256, 0, stream>>>(x, agg, ampv, batch, gfeat, gcnt, N, GRCH);
    k_tail<<<128, 256, 0, stream>>>(gfeat, gcnt, W_post, b_post, W_lin, b_lin, Zin,
                                    g1, be1, W2, b2, g2, be2,
                                    Wr1, br1, gr1, ber1, Wr2, br2, gr2, ber2,
                                    W_out, b_out, z2b, z3b, z4b, out, bar, G);
}

// Round 13
// 235.803 us; speedup vs baseline: 1.1655x; 1.1655x over previous
//
#include <hip/hip_runtime.h>
#include <hip/hip_bf16.h>

using bf16 = __hip_bfloat16;

#define F 64
#define HG 128
#define HL 128
#define AVG_LOG_INV 0.45511961331341866f  // 1/log(9)
#define BSH 5            // 32 nodes per bucket
#define BNODES 32
#define BCAP 1024        // per-bucket record capacity (mean 512, +22 sigma)
#define BTILE 8192       // edges per k_bucket block
#define NBMAX 1664       // LDS hist array size (>= NB)

typedef short short8 __attribute__((ext_vector_type(8)));
typedef float floatx4 __attribute__((ext_vector_type(4)));

__device__ __forceinline__ float b2f(bf16 v) { return __bfloat162float(v); }
__device__ __forceinline__ bf16 f2b(float v) { return __float2bfloat16(v); }
__device__ __forceinline__ short f2bs(float v) { bf16 h = f2b(v); return *(short*)&h; }

__device__ __forceinline__ unsigned packbf2(float x, float y) {
    bf16 a = f2b(x), b = f2b(y);
    unsigned short ua = *(unsigned short*)&a, ub = *(unsigned short*)&b;
    return ((unsigned)ub << 16) | (unsigned)ua;
}

__device__ __forceinline__ float wave_sum(float v) {
    #pragma unroll
    for (int m = 32; m > 0; m >>= 1) v += __shfl_xor(v, m);
    return v;
}

// MFMA AB staging + fused init (zero gcur/gfeat/gcnt, compute uc in block 0)
__global__ void k_ab_mfma(const float* __restrict__ x, const float* __restrict__ W_pre,
                          bf16* __restrict__ AB, int N,
                          int* __restrict__ gcur, float* __restrict__ gfeat,
                          int* __restrict__ gcnt, int NB, int GF, int G,
                          const float* __restrict__ W_edge, const float* __restrict__ b_edge,
                          const float* __restrict__ b_pre, float* __restrict__ uc) {
    int gtid = blockIdx.x * blockDim.x + threadIdx.x;
    int gstr = gridDim.x * blockDim.x;
    for (int i = gtid; i < GF; i += gstr) gfeat[i] = 0.f;
    for (int i = gtid; i < NB; i += gstr) gcur[i] = 0;
    for (int i = gtid; i < G; i += gstr) gcnt[i] = 0;
    if (blockIdx.x == 0 && threadIdx.x < 64) {
        int f = threadIdx.x;
        float u = 0.f, c = b_pre[f];
        for (int k = 0; k < 64; k++) {
            float w3 = W_pre[(128 + k) * 64 + f];
            u += W_edge[k] * w3;
            c += b_edge[k] * w3;
        }
        uc[f] = u; uc[64 + f] = c;
    }

    __shared__ unsigned short wt[128 * 72];  // wt[m][k]
    for (int idx = threadIdx.x; idx < 8192; idx += 256) {
        int k = idx >> 7, m = idx & 127;
        float v = W_pre[((m & 64) + k) * 64 + (m & 63)];
        wt[m * 72 + k] = (unsigned short)f2bs(v);
    }
    __syncthreads();

    int lane = threadIdx.x & 63;
    int row = lane & 15, quad = lane >> 4;
    int w = (blockIdx.x * blockDim.x + threadIdx.x) >> 6;
    int nwaves = (gridDim.x * blockDim.x) >> 6;
    int ntiles = (N + 15) >> 4;

    for (int tile = w; tile < ntiles; tile += nwaves) {
        int m0 = tile << 4;
        int node_a = m0 + row; if (node_a >= N) node_a = N - 1;
        short8 a[2];
        #pragma unroll
        for (int h = 0; h < 2; h++) {
            const float* xp = x + (size_t)node_a * 64 + h * 32 + quad * 8;
            floatx4 v0 = *(const floatx4*)xp;
            floatx4 v1 = *(const floatx4*)(xp + 4);
            #pragma unroll
            for (int j = 0; j < 4; j++) { a[h][j] = f2bs(v0[j]); a[h][4 + j] = f2bs(v1[j]); }
        }
        #pragma unroll
        for (int t = 0; t < 8; t++) {
            int fbase = t * 16;
            floatx4 c = {0.f, 0.f, 0.f, 0.f};
            #pragma unroll
            for (int h = 0; h < 2; h++) {
                short8 b = *(const short8*)(wt + (fbase + row) * 72 + h * 32 + quad * 8);
                c = __builtin_amdgcn_mfma_f32_16x16x32_bf16(a[h], b, c, 0, 0, 0);
            }
            #pragma unroll
            for (int r = 0; r < 4; r++) {
                int node = m0 + quad * 4 + r;
                if (node < N) AB[(size_t)node * 128 + fbase + row] = f2b(c[r]);
            }
        }
    }
}

// bucket partition: bucket = dst>>5 (32 nodes/bucket). LDS-aggregated cursor
// reservations; int4-vectorized edge reads. rec = ((dst<<16)|src, ea_f32bits).
// REQUIRES N <= 65536. 1024 threads.
__global__ void k_bucket(const int* __restrict__ ei, const float* __restrict__ ea,
                         int* __restrict__ gcur, int2* __restrict__ gout,
                         int E, int NB) {
    __shared__ int2 recs[BTILE];
    __shared__ int hist[NBMAX], gst[NBMAX], lrk[NBMAX];
    int t = threadIdx.x;  // 1024
    for (int b = t; b < NB; b += 1024) hist[b] = 0;
    __syncthreads();
    int base = blockIdx.x * BTILE;
    int lim = E - base; if (lim > BTILE) lim = BTILE;
    int nq = lim >> 2;
    const int4* src4 = (const int4*)(ei + base);
    const int4* dst4 = (const int4*)(ei + E + base);
    const float4* ea4 = (const float4*)(ea + base);
    for (int q = t; q < nq; q += 1024) {
        int4 s = src4[q], d = dst4[q];
        float4 v = ea4[q];
        int i = q * 4;
        recs[i]     = make_int2((d.x << 16) | s.x, __float_as_int(v.x));
        recs[i + 1] = make_int2((d.y << 16) | s.y, __float_as_int(v.y));
        recs[i + 2] = make_int2((d.z << 16) | s.z, __float_as_int(v.z));
        recs[i + 3] = make_int2((d.w << 16) | s.w, __float_as_int(v.w));
        atomicAdd(&hist[d.x >> BSH], 1);
        atomicAdd(&hist[d.y >> BSH], 1);
        atomicAdd(&hist[d.z >> BSH], 1);
        atomicAdd(&hist[d.w >> BSH], 1);
    }
    for (int i = (nq << 2) + t; i < lim; i += 1024) {
        int e = base + i;
        int src = ei[e], dst = ei[E + e];
        recs[i] = make_int2((dst << 16) | src, __float_as_int(ea[e]));
        atomicAdd(&hist[dst >> BSH], 1);
    }
    __syncthreads();
    for (int b = t; b < NB; b += 1024) {
        int h = hist[b];
        lrk[b] = 0;
        gst[b] = (h > 0) ? atomicAdd(&gcur[b], h) : 0;
    }
    __syncthreads();
    for (int i = t; i < lim; i += 1024) {
        int2 r = recs[i];
        int b = ((unsigned)r.x) >> (16 + BSH);
        int k = atomicAdd(&lrk[b], 1);
        int pos = gst[b] + k;
        if (pos < BCAP) gout[(size_t)b * BCAP + pos] = r;
    }
}

// one block (512 thr, 8 waves) per bucket (32 nodes): LDS counting-sort,
// then per-node reduction. Gathers software-pipelined 4-deep.  (R9-proven)
__global__ void k_edge(const bf16* __restrict__ AB, const int2* __restrict__ gout,
                       const int* __restrict__ gcur, const float* __restrict__ uc,
                       bf16* __restrict__ agg, float* __restrict__ ampv, int N) {
    __shared__ int2 recs[BCAP], sortd[BCAP];
    __shared__ int ncnt[BNODES], nofs[BNODES], nrank[BNODES];
    int t = threadIdx.x;  // 512
    int b = blockIdx.x;
    int nn = N - b * BNODES; if (nn > BNODES) nn = BNODES;
    int ecnt = gcur[b]; if (ecnt > BCAP) ecnt = BCAP;

    for (int i = t; i < ecnt; i += 512) recs[i] = gout[(size_t)b * BCAP + i];
    if (t < BNODES) { ncnt[t] = 0; nrank[t] = 0; }
    __syncthreads();
    for (int i = t; i < ecnt; i += 512)
        atomicAdd(&ncnt[((unsigned)recs[i].x >> 16) & (BNODES - 1)], 1);
    __syncthreads();
    if (t < BNODES) {  // exclusive scan over node counts
        int v = ncnt[t], inc = v;
        #pragma unroll
        for (int m = 1; m < BNODES; m <<= 1) { int u = __shfl_up(inc, m); if (t >= m) inc += u; }
        nofs[t] = inc - v;
    }
    __syncthreads();
    for (int i = t; i < ecnt; i += 512) {
        int2 r = recs[i];
        int nl = ((unsigned)r.x >> 16) & (BNODES - 1);
        int k = atomicAdd(&nrank[nl], 1);
        sortd[nofs[nl] + k] = r;
    }
    __syncthreads();

    int lane = t & 63, w = t >> 6;  // 8 waves
    int half = lane & 31, hi32 = lane >> 5;
    float2 u2 = *(const float2*)(uc + 2 * half);
    float2 c2 = *(const float2*)(uc + 64 + 2 * half);

    for (int nl = w; nl < nn; nl += 8) {
        int n = b * BNODES + nl;
        int lo = nofs[nl], cnt = ncnt[nl], hi = lo + cnt;

        unsigned apack = *(const unsigned*)(AB + (size_t)n * 128 + 2 * half);
        float acx = __uint_as_float(apack << 16) + c2.x;
        float acy = __uint_as_float(apack & 0xffff0000u) + c2.y;

        float sx = 0.f, sy = 0.f, qx = 0.f, qy = 0.f;
        float mnx = 3.4e38f, mny = 3.4e38f, mxx = -3.4e38f, mxy = -3.4e38f;

        auto acc2 = [&](unsigned bp, float eav) {
            float bx = __uint_as_float(bp << 16);
            float by = __uint_as_float(bp & 0xffff0000u);
            float m0 = fmaf(eav, u2.x, acx) + bx;
            float m1 = fmaf(eav, u2.y, acy) + by;
            sx += m0; qx = fmaf(m0, m0, qx);
            sy += m1; qy = fmaf(m1, m1, qy);
            mnx = fminf(mnx, m0); mxx = fmaxf(mxx, m0);
            mny = fminf(mny, m1); mxy = fmaxf(mxy, m1);
        };
        auto gaddr = [&](int sn) {
            return (const unsigned*)(AB + (size_t)sn * 128 + 64 + 2 * half);
        };

        for (int base = lo; base < hi; base += 64) {
            int nb = hi - base; if (nb > 64) nb = 64;
            int2 rec = (lane < nb) ? sortd[base + lane] : make_int2(0, 0);
            int vsn = rec.x & 0xFFFF;
            float vea = __int_as_float(rec.y);
            int i = 0;
            for (; i + 8 <= nb; i += 8) {  // 4 pairs in flight
                int sn0 = __shfl(vsn, i + hi32);
                int sn1 = __shfl(vsn, i + 2 + hi32);
                int sn2 = __shfl(vsn, i + 4 + hi32);
                int sn3 = __shfl(vsn, i + 6 + hi32);
                float e0 = __shfl(vea, i + hi32);
                float e1 = __shfl(vea, i + 2 + hi32);
                float e2 = __shfl(vea, i + 4 + hi32);
                float e3 = __shfl(vea, i + 6 + hi32);
                unsigned b0 = *gaddr(sn0);
                unsigned b1 = *gaddr(sn1);
                unsigned b2 = *gaddr(sn2);
                unsigned b3 = *gaddr(sn3);
                acc2(b0, e0); acc2(b1, e1); acc2(b2, e2); acc2(b3, e3);
            }
            for (; i + 2 <= nb; i += 2) {
                int   sn = __shfl(vsn, i + hi32);
                float ev = __shfl(vea, i + hi32);
                acc2(*gaddr(sn), ev);
            }
            if (i < nb) {  // odd tail: only hi32==0 lanes accumulate
                int   sn = __shfl(vsn, i);
                float ev = __shfl(vea, i);
                unsigned bp = *gaddr(sn);
                if (hi32 == 0) acc2(bp, ev);
            }
        }
        sx += __shfl_xor(sx, 32); sy += __shfl_xor(sy, 32);
        qx += __shfl_xor(qx, 32); qy += __shfl_xor(qy, 32);
        mnx = fminf(mnx, __shfl_xor(mnx, 32)); mny = fminf(mny, __shfl_xor(mny, 32));
        mxx = fmaxf(mxx, __shfl_xor(mxx, 32)); mxy = fmaxf(mxy, __shfl_xor(mxy, 32));

        float c1 = (cnt > 0) ? (float)cnt : 1.f;
        float inv = 1.f / c1;
        float mex = sx * inv, mey = sy * inv;
        float vx = qx * inv - mex * mex; if (vx < 0.f) vx = 0.f;
        float vy = qy * inv - mey * mey; if (vy < 0.f) vy = 0.f;
        float sdx = sqrtf(vx + 1e-5f), sdy = sqrtf(vy + 1e-5f);
        if (cnt == 0) { mnx = mny = mxx = mxy = 0.f; }

        size_t ob = (size_t)n * 256 + 2 * half;
        if (hi32 == 0) {
            *(unsigned*)(agg + ob)       = packbf2(mex, mey);
            *(unsigned*)(agg + ob + 64)  = packbf2(mnx, mny);
        } else {
            *(unsigned*)(agg + ob + 128) = packbf2(mxx, mxy);
            *(unsigned*)(agg + ob + 192) = packbf2(sdx, sdy);
        }
        if (lane == 0) ampv[n] = logf(c1 + 1.f) * AVG_LOG_INV;
    }
}

// chunked per-graph SUM of 832-dim feature vector [x | agg | agg*amp | agg/amp]
// flushes use native fp32 atomics (unsafeAtomicAdd) to avoid CAS loops.
__global__ void k_greduce2(const float* __restrict__ x, const bf16* __restrict__ agg,
                           const float* __restrict__ ampv, const int* __restrict__ batch,
                           float* __restrict__ gfeat, int* __restrict__ gcnt,
                           int N, int chunk) {
    int t = threadIdx.x;  // 256
    int lo = blockIdx.x * chunk;
    int hi = lo + chunk; if (hi > N) hi = N;
    if (lo >= hi) return;
    int curg = batch[lo];
    float s1 = 0.f, s2 = 0.f, s3 = 0.f, sx = 0.f;
    int cnt = 0;
    for (int n = lo; n < hi; n++) {
        int g = batch[n];
        if (g != curg) {
            float* gf = gfeat + (size_t)curg * 832;
            unsafeAtomicAdd(&gf[64 + t], s1);
            unsafeAtomicAdd(&gf[320 + t], s2);
            unsafeAtomicAdd(&gf[576 + t], s3);
            if (t < 64) unsafeAtomicAdd(&gf[t], sx);
            if (t == 0) atomicAdd(&gcnt[curg], cnt);
            s1 = s2 = s3 = sx = 0.f; cnt = 0; curg = g;
        }
        float amp = ampv[n];
        float av = b2f(agg[(size_t)n * 256 + t]);
        s1 += av; s2 += av * amp; s3 += av / amp;
        if (t < 64) sx += x[(size_t)n * 64 + t];
        cnt++;
    }
    float* gf = gfeat + (size_t)curg * 832;
    unsafeAtomicAdd(&gf[64 + t], s1);
    unsafeAtomicAdd(&gf[320 + t], s2);
    unsafeAtomicAdd(&gf[576 + t], s3);
    if (t < 64) unsafeAtomicAdd(&gf[t], sx);
    if (t == 0) atomicAdd(&gcnt[curg], cnt);
}

// Zin[g] = ((gfeat[g]/cnt) @ W_post + b_post) @ W_lin + b_lin ; zero if empty graph
__global__ void k_post1(const float* __restrict__ gfeat, const int* __restrict__ gcnt,
                        const float* __restrict__ W_post, const float* __restrict__ b_post,
                        const float* __restrict__ W_lin, const float* __restrict__ b_lin,
                        float* __restrict__ Zin) {
    int g = blockIdx.x, j = threadIdx.x;  // 128
    __shared__ float feat[832];
    __shared__ float z1[128];
    int cg = gcnt[g];
    float r = 1.f / ((cg > 0) ? (float)cg : 1.f);
    for (int i = j; i < 832; i += 128) feat[i] = gfeat[(size_t)g * 832 + i] * r;
    __syncthreads();
    float acc = b_post[j];
    for (int k = 0; k < 832; k++) acc += feat[k] * W_post[k * 128 + j];
    z1[j] = acc;
    __syncthreads();
    float a2 = b_lin[j];
    for (int k = 0; k < 128; k++) a2 += z1[k] * W_lin[k * 128 + j];
    if (cg == 0) a2 = 0.f;
    Zin[g * 128 + j] = a2;
}

// column-parallel MLP layer: block j computes output column j of
//   out = relu( BN(in' @ W + bias; gamma,beta) [+ res] ), in' = relu(BN(in)) if g_in
__global__ void k_mlpcol(const float* __restrict__ in, const float* __restrict__ W,
                         const float* __restrict__ bias,
                         const float* __restrict__ gamma, const float* __restrict__ beta,
                         const float* __restrict__ res,
                         const float* __restrict__ g_in, const float* __restrict__ be_in,
                         float* __restrict__ outp) {
    __shared__ float A[64 * 129];
    __shared__ float part[4 * 64];
    int t = threadIdx.x;  // 256
    int j = blockIdx.x;   // 128

    for (int i = t; i < 8192; i += 256) A[(i >> 7) * 129 + (i & 127)] = in[i];
    __syncthreads();

    if (g_in) {
        if (t < 128) {
            int c = t;
            float mu = 0.f;
            for (int r = 0; r < 64; r++) mu += A[r * 129 + c];
            mu *= (1.f / 64.f);
            float var = 0.f;
            for (int r = 0; r < 64; r++) { float d = A[r * 129 + c] - mu; var += d * d; }
            var *= (1.f / 64.f);
            float sc = rsqrtf(var + 1e-5f) * g_in[c], sh = be_in[c];
            for (int r = 0; r < 64; r++) {
                float v = (A[r * 129 + c] - mu) * sc + sh;
                A[r * 129 + c] = v > 0.f ? v : 0.f;
            }
        }
        __syncthreads();
    }

    int r = t & 63, q = t >> 6;
    float acc = 0.f;
    int k0 = q * 32;
    #pragma unroll
    for (int k = 0; k < 32; k++) acc += A[r * 129 + k0 + k] * W[(k0 + k) * 128 + j];
    part[q * 64 + r] = acc;
    __syncthreads();

    if (t < 64) {
        float v = part[t] + part[64 + t] + part[128 + t] + part[192 + t] + bias[j];
        float mu = wave_sum(v) * (1.f / 64.f);
        float d = v - mu;
        float var = wave_sum(d * d) * (1.f / 64.f);
        float o = d * rsqrtf(var + 1e-5f) * gamma[j] + beta[j];
        if (res) o += res[t * 128 + j];
        outp[t * 128 + j] = o > 0.f ? o : 0.f;
    }
}

__global__ void k_out(const float* __restrict__ z4, const float* __restrict__ W_out,
                      const float* b_out, float* __restrict__ out) {
    int g = threadIdx.x;  // 64
    float acc = b_out[0];
    for (int j = 0; j < 128; j++) acc += z4[g * 128 + j] * W_out[j];
    out[g] = acc;
}

extern "C" void kernel_launch(void* const* d_in, const int* in_sizes, int n_in,
                              void* d_out, int out_size, void* d_ws, size_t ws_size,
                              hipStream_t stream) {
    const float* x      = (const float*)d_in[0];
    const int*   ei     = (const int*)d_in[1];
    const float* ea     = (const float*)d_in[2];
    const int*   batch  = (const int*)d_in[3];
    const float* W_edge = (const float*)d_in[4];
    const float* b_edge = (const float*)d_in[5];
    const float* W_pre  = (const float*)d_in[6];
    const float* b_pre  = (const float*)d_in[7];
    const float* W_post = (const float*)d_in[8];
    const float* b_post = (const float*)d_in[9];
    const float* W_lin  = (const float*)d_in[10];
    const float* b_lin  = (const float*)d_in[11];
    const float* g1     = (const float*)d_in[12];
    const float* be1    = (const float*)d_in[13];
    const float* W2     = (const float*)d_in[14];
    const float* b2     = (const float*)d_in[15];
    const float* g2     = (const float*)d_in[16];
    const float* be2    = (const float*)d_in[17];
    const float* Wr1    = (const float*)d_in[18];
    const float* br1    = (const float*)d_in[19];
    const float* gr1    = (const float*)d_in[20];
    const float* ber1   = (const float*)d_in[21];
    const float* Wr2    = (const float*)d_in[22];
    const float* br2    = (const float*)d_in[23];
    const float* gr2    = (const float*)d_in[24];
    const float* ber2   = (const float*)d_in[25];
    const float* W_out  = (const float*)d_in[26];
    const float* b_out  = (const float*)d_in[27];
    float* out = (float*)d_out;

    const int N = in_sizes[0] / F;      // 50000  (must be <= 65536 for record packing)
    const int E = in_sizes[1] / 2;      // 800000
    const int G = out_size;             // 64
    const int NB = (N + BNODES - 1) >> BSH;  // 1563 buckets

    char* p = (char*)d_ws;
    auto alloc = [&](size_t nbytes) { void* r = p; p += (nbytes + 255) & ~(size_t)255; return r; };
    bf16*  AB     = (bf16*)alloc((size_t)N * 128 * sizeof(bf16));
    bf16*  agg    = (bf16*)alloc((size_t)N * 256 * sizeof(bf16));
    float* ampv   = (float*)alloc((size_t)N * sizeof(float));
    int*   gcur   = (int*)alloc((size_t)NB * sizeof(int));
    int2*  gout   = (int2*)alloc((size_t)NB * BCAP * sizeof(int2));
    float* uc     = (float*)alloc(128 * sizeof(float));
    float* gfeat  = (float*)alloc((size_t)G * 832 * sizeof(float));
    int*   gcnt   = (int*)alloc((size_t)G * sizeof(int));
    float* Zin    = (float*)alloc(64 * 128 * sizeof(float));
    float* z2b    = (float*)alloc(64 * 128 * sizeof(float));
    float* z3b    = (float*)alloc(64 * 128 * sizeof(float));
    float* z4b    = (float*)alloc(64 * 128 * sizeof(float));

    const int GF = G * 832;
    const int GRB = 1024;
    const int GRCH = (N + GRB - 1) / GRB;
    const int ABB = ((N + 15) / 16 + 3) / 4;   // 782 blocks
    const int NBT = (E + BTILE - 1) / BTILE;   // 98 blocks

    k_ab_mfma<<<ABB, 256, 0, stream>>>(x, W_pre, AB, N, gcur, gfeat, gcnt, NB, GF, G,
                                       W_edge, b_edge, b_pre, uc);
    k_bucket<<<NBT, 1024, 0, stream>>>(ei, ea, gcur, gout, E, NB);
    k_edge<<<NB, 512, 0, stream>>>(AB, gout, gcur, uc, agg, ampv, N);
    k_greduce2<<<GRB, 256, 0, stream>>>(x, agg, ampv, batch, gfeat, gcnt, N, GRCH);
    k_post1<<<G, 128, 0, stream>>>(gfeat, gcnt, W_post, b_post, W_lin, b_lin, Zin);
    k_mlpcol<<<HG, 256, 0, stream>>>(Zin, W2, b2, g2, be2, nullptr, g1, be1, z2b);
    k_mlpcol<<<HL, 256, 0, stream>>>(z2b, Wr1, br1, gr1, ber1, nullptr, nullptr, nullptr, z3b);
    k_mlpcol<<<HL, 256, 0, stream>>>(z3b, Wr2, br2, gr2, ber2, z2b, nullptr, nullptr, z4b);
    k_out<<<1, 64, 0, stream>>>(z4b, W_out, b_out, out);
}